// Round 7
// baseline (370.221 us; speedup 1.0000x reference)
//
#include <hip/hip_runtime.h>
#include <math.h>

static inline int cdiv(long long a, int b){ return (int)((a + b - 1) / b); }
#define DEVINL __device__ __forceinline__

DEVINL float4 relu4(const float* a){
  return make_float4(fmaxf(a[0],0.f), fmaxf(a[1],0.f), fmaxf(a[2],0.f), fmaxf(a[3],0.f));
}

// tap index for sibling pair: d = o' - o componentwise; k = (dx+1)*9+(dy+1)*3+(dz+1)
DEVINL int sib_k(int o, int op){
  return 13 + 9*(((op>>2)&1) - ((o>>2)&1))
            + 3*(((op>>1)&1) - ((o>>1)&1))
            +   ((op&1) - (o&1));
}

// LDS geometry: features [child 8][parent 64][C + pad], odd parent stride -> 2-way banks (free)
#define PS32 35         // parent stride for 32-float rows
#define CS32 2241       // child stride (odd)
#define LDS32 (7*CS32 + 64*PS32)   // 17933 floats
#define PS16 19         // parent stride for 16-float (a8|b8) rows
#define CS16 1217
#define LDS16 (7*CS16 + 64*PS16)   // 9735 floats

// ---------- remainder list build ----------
__global__ void k_rinit(int* __restrict__ cnt, int n){
  int i = blockIdx.x*blockDim.x + threadIdx.x;
  if (i < n) cnt[i] = 0;
}

__global__ void k_rbuild(const int* __restrict__ nin, const int* __restrict__ nout,
                         int* __restrict__ cnt, int* __restrict__ rem, int P, int N){
  int p = blockIdx.x*blockDim.x + threadIdx.x;
  if (p >= 27*P) return;
  int oi = nout[p];
  if (oi >= N) return;
  int j = nin[p];
  if ((oi >> 3) == (j >> 3)) return;
  int k = p / P;
  int pos = atomicAdd(&cnt[oi], 1);
  rem[(size_t)oi*20 + pos] = (j << 5) | k;
}

// ---------- weight repack into per-(o,op) scalar-friendly tables ----------
// Wq1 [y4][o8][op8][cc32][8]          : 65536
// WqA [l3][o8][cg2][op8][cc32][4]     : 49152
// WqB0[l3][o8][cg4][op8][cc8][4]      : 24576
// WqB1[l3][o8][op8][cc8][8]           : 12288
// WqC [o8][op8][cc32]                 : 2048
__global__ void k_repack(const float* __restrict__ Wconv, const float* __restrict__ W00,
                         const float* __restrict__ W01, const float* __restrict__ W11,
                         const float* __restrict__ Wcls,
                         float* __restrict__ Wq1, float* __restrict__ WqA,
                         float* __restrict__ WqB0, float* __restrict__ WqB1,
                         float* __restrict__ WqC){
  int idx = blockIdx.x*blockDim.x + threadIdx.x;
  if (idx < 65536){
    int j = idx&7, cc = (idx>>3)&31, op = (idx>>8)&7, o = (idx>>11)&7, y = idx>>14;
    int kk = sib_k(o, op);
    Wq1[idx] = Wconv[((size_t)(kk*32+cc))*32 + y*8 + j];
    return;
  }
  idx -= 65536;
  if (idx < 49152){
    int j = idx&3, cc = (idx>>2)&31, op = (idx>>7)&7, cg = (idx>>10)&1, o = (idx>>11)&7, l = idx>>14;
    int kk = sib_k(o, op);
    WqA[idx] = W00[(size_t)l*6912 + (kk*32+cc)*8 + cg*4 + j];
    return;
  }
  idx -= 49152;
  if (idx < 24576){
    int j = idx&3, cc = (idx>>2)&7, op = (idx>>5)&7, cg = (idx>>8)&3, o = (idx>>10)&7, l = idx>>13;
    int kk = sib_k(o, op);
    WqB0[idx] = W01[(size_t)l*3456 + (kk*8+cc)*16 + cg*4 + j];
    return;
  }
  idx -= 24576;
  if (idx < 12288){
    int j = idx&7, cc = (idx>>3)&7, op = (idx>>6)&7, o = (idx>>9)&7, l = idx>>12;
    int kk = sib_k(o, op);
    WqB1[idx] = W11[(size_t)l*1728 + (kk*8+cc)*8 + j];
    return;
  }
  idx -= 12288;
  if (idx < 2048){
    int cc = idx&31, op = (idx>>5)&7, o = idx>>8;
    int kk = sib_k(o, op);
    WqC[idx] = Wcls[kk*32 + cc];
  }
}

// ---------- stage 512 rows x 32 floats into LDS [8][64][PS32] ----------
DEVINL void stage32(float* Ws, const float* __restrict__ src, int blk){
  for (int m = threadIdx.x; m < 4096; m += 512){
    int r = m >> 3, q = m & 7;
    float4 v = ((const float4*)(src + ((size_t)(blk*512 + r))*32))[q];
    int c = r & 7, p = r >> 3;
    float* d = &Ws[c*CS32 + p*PS32 + q*4];
    d[0]=v.x; d[1]=v.y; d[2]=v.z; d[3]=v.w;
  }
}

// ---------- up: f_tmp[(n*8+kk)*32+c] = relu(x[n]·W_up[kk]+b_up) ----------
// block 512 = 8 waves(=cout octile) x 64 lanes(=n); grid (Nn/64, 8=kk)
__global__ __launch_bounds__(512) void k_up(const float* __restrict__ x,
    const float* __restrict__ Wup, const float* __restrict__ bup,
    float* __restrict__ f, int Nn){
  __shared__ float Ws[64*66];
  const int kk = blockIdx.y;
  for (int m = threadIdx.x; m < 1024; m += 512){
    int r = m >> 4, q = m & 15;
    float4 v = ((const float4*)(x + ((size_t)(blockIdx.x*64 + r))*64))[q];
    float* d = &Ws[r*66 + q*4];
    d[0]=v.x; d[1]=v.y; d[2]=v.z; d[3]=v.w;
  }
  __syncthreads();
  int w = __builtin_amdgcn_readfirstlane(threadIdx.x >> 6);
  int nl = threadIdx.x & 63;
  int c0 = w*4;
  const float* wb = Wup + (size_t)kk*2048 + c0;   // uniform
  float acc[4] = {bup[c0], bup[c0+1], bup[c0+2], bup[c0+3]};
  const float* fvp = &Ws[nl*66];
#pragma unroll
  for (int cc = 0; cc < 64; ++cc){
    float fx = fvp[cc];
    acc[0]=fmaf(fx, wb[cc*32+0], acc[0]); acc[1]=fmaf(fx, wb[cc*32+1], acc[1]);
    acc[2]=fmaf(fx, wb[cc*32+2], acc[2]); acc[3]=fmaf(fx, wb[cc*32+3], acc[3]);
  }
  int n = blockIdx.x*64 + nl;
  *(float4*)(f + ((size_t)n*8 + kk)*32 + c0) = relu4(acc);
}

// ---------- conv1: 27x32x32 sibling-static, scalar weights; grid (N/512, 4=c-octpair) ----------
__global__ __launch_bounds__(512) void k_conv1(const float* __restrict__ fin,
    const float* __restrict__ Wq1, const float* __restrict__ Wconv,
    const float* __restrict__ bg,
    const int* __restrict__ cnt, const int* __restrict__ rem,
    float* __restrict__ fout, int N){
  __shared__ float Ws[LDS32];
  stage32(Ws, fin, blockIdx.x);
  __syncthreads();
  int o = __builtin_amdgcn_readfirstlane(threadIdx.x >> 6);
  int p = threadIdx.x & 63;
  int row = blockIdx.x*512 + p*8 + o;
  int cb = blockIdx.y*8;
  const float* wb = Wq1 + (size_t)blockIdx.y*16384 + o*2048;  // uniform
  float acc[8];
#pragma unroll
  for (int j = 0; j < 8; ++j) acc[j] = bg[cb+j];
#pragma unroll 1
  for (int op = 0; op < 8; ++op){
    const float* fvp = &Ws[op*CS32 + p*PS32];
    const float* wop = wb + op*256;
#pragma unroll
    for (int cc = 0; cc < 32; ++cc){
      float fx = fvp[cc];
#pragma unroll
      for (int j = 0; j < 8; ++j) acc[j] = fmaf(fx, wop[cc*8+j], acc[j]);
    }
  }
  int nrm = cnt[row];
  for (int s = 0; s < nrm; ++s){
    int e = rem[(size_t)row*20 + s];
    int kk = e & 31, jr = e >> 5;
    const float* fr = fin + (size_t)jr*32;
    const float* wg = Wconv + (size_t)kk*1024 + cb;
#pragma unroll
    for (int cc = 0; cc < 32; ++cc){
      float fx = fr[cc];
#pragma unroll
      for (int j = 0; j < 8; ++j) acc[j] = fmaf(fx, wg[cc*32+j], acc[j]);
    }
  }
  *(float4*)(fout + (size_t)row*32 + cb)     = relu4(acc);
  *(float4*)(fout + (size_t)row*32 + cb + 4) = relu4(acc+4);
}

// ---------- blk_a: a8 = relu(sconv32->8+b00); b8 = relu(f@W10+b10); grid (N/512, 2=cg) ----------
__global__ __launch_bounds__(512) void k_blk_a(const float* __restrict__ fO,
    const float* __restrict__ WqA_l, const float* __restrict__ W00_l,
    const float* __restrict__ b00,
    const float* __restrict__ W10_l, const float* __restrict__ b10,
    const int* __restrict__ cnt, const int* __restrict__ rem,
    float* __restrict__ a8, float* __restrict__ b8, int N){
  __shared__ float Ws[LDS32];
  stage32(Ws, fO, blockIdx.x);
  __syncthreads();
  int o = __builtin_amdgcn_readfirstlane(threadIdx.x >> 6);
  int p = threadIdx.x & 63;
  int row = blockIdx.x*512 + p*8 + o;
  int cg = blockIdx.y;
  const float* wb = WqA_l + o*2048 + cg*1024;   // uniform
  float acc[4];
#pragma unroll
  for (int j = 0; j < 4; ++j) acc[j] = b00[cg*4+j];
#pragma unroll 1
  for (int op = 0; op < 8; ++op){
    const float* fvp = &Ws[op*CS32 + p*PS32];
    const float* wop = wb + op*128;
#pragma unroll
    for (int cc = 0; cc < 32; ++cc){
      float fx = fvp[cc];
#pragma unroll
      for (int j = 0; j < 4; ++j) acc[j] = fmaf(fx, wop[cc*4+j], acc[j]);
    }
  }
  int nrm = cnt[row];
  for (int s = 0; s < nrm; ++s){
    int e = rem[(size_t)row*20 + s];
    int kk = e & 31, jr = e >> 5;
    const float* fr = fO + (size_t)jr*32;
    const float* wg = W00_l + (size_t)kk*256 + cg*4;
#pragma unroll
    for (int cc = 0; cc < 32; ++cc){
      float fx = fr[cc];
#pragma unroll
      for (int j = 0; j < 4; ++j) acc[j] = fmaf(fx, wg[cc*8+j], acc[j]);
    }
  }
  *(float4*)(a8 + (size_t)row*8 + cg*4) = relu4(acc);
  // dense branch: own row, couts cg*4..+4
  const float* fvo = &Ws[o*CS32 + p*PS32];
  float accb[4];
#pragma unroll
  for (int j = 0; j < 4; ++j) accb[j] = b10[cg*4+j];
#pragma unroll
  for (int cc = 0; cc < 32; ++cc){
    float fx = fvo[cc];
#pragma unroll
    for (int j = 0; j < 4; ++j) accb[j] = fmaf(fx, W10_l[cc*8 + cg*4 + j], accb[j]);
  }
  *(float4*)(b8 + (size_t)row*8 + cg*4) = relu4(accb);
}

// ---------- blk_b: fout[:,0:16] += sconv8->16(a8)+b01 ; fout[:,16:32] += relu(sconv8->8(b8)+b11)@W12+b12
// grid (N/512, 4=cg) ----------
__global__ __launch_bounds__(512) void k_blk_b(const float* __restrict__ a8,
    const float* __restrict__ b8,
    const float* __restrict__ WqB0_l, const float* __restrict__ W01_l, const float* __restrict__ b01,
    const float* __restrict__ WqB1_l, const float* __restrict__ W11_l, const float* __restrict__ b11,
    const float* __restrict__ W12_l, const float* __restrict__ b12,
    const int* __restrict__ cnt, const int* __restrict__ rem,
    float* __restrict__ fout, int N){
  __shared__ float Ws[LDS16];
  for (int m = threadIdx.x; m < 1024; m += 512){
    int r = m >> 1, q = m & 1;
    float4 va = ((const float4*)(a8 + ((size_t)(blockIdx.x*512 + r))*8))[q];
    float4 vb = ((const float4*)(b8 + ((size_t)(blockIdx.x*512 + r))*8))[q];
    int c = r & 7, p = r >> 3;
    float* d = &Ws[c*CS16 + p*PS16 + q*4];
    d[0]=va.x; d[1]=va.y; d[2]=va.z; d[3]=va.w;
    d[8]=vb.x; d[9]=vb.y; d[10]=vb.z; d[11]=vb.w;
  }
  __syncthreads();
  int o = __builtin_amdgcn_readfirstlane(threadIdx.x >> 6);
  int p = threadIdx.x & 63;
  int row = blockIdx.x*512 + p*8 + o;
  int cg = blockIdx.y;
  const float* wb0 = WqB0_l + o*1024 + cg*256;  // uniform
  const float* wb1 = WqB1_l + o*512;            // uniform
  float p0[4], t8[8];
#pragma unroll
  for (int j = 0; j < 4; ++j) p0[j] = b01[cg*4+j];
#pragma unroll
  for (int j = 0; j < 8; ++j) t8[j] = b11[j];
#pragma unroll 1
  for (int op = 0; op < 8; ++op){
    const float* avp = &Ws[op*CS16 + p*PS16];
    const float* wop0 = wb0 + op*32;
    const float* wop1 = wb1 + op*64;
#pragma unroll
    for (int cc = 0; cc < 8; ++cc){
      float fa = avp[cc], fb = avp[cc+8];
#pragma unroll
      for (int j = 0; j < 4; ++j) p0[j] = fmaf(fa, wop0[cc*4+j], p0[j]);
#pragma unroll
      for (int j = 0; j < 8; ++j) t8[j] = fmaf(fb, wop1[cc*8+j], t8[j]);
    }
  }
  int nrm = cnt[row];
  for (int s = 0; s < nrm; ++s){
    int e = rem[(size_t)row*20 + s];
    int kk = e & 31, jr = e >> 5;
    const float* fra = a8 + (size_t)jr*8;
    const float* frb = b8 + (size_t)jr*8;
    const float* wg0 = W01_l + (size_t)kk*128 + cg*4;
    const float* wg1 = W11_l + (size_t)kk*64;
#pragma unroll
    for (int cc = 0; cc < 8; ++cc){
      float fa = fra[cc], fb = frb[cc];
#pragma unroll
      for (int j = 0; j < 4; ++j) p0[j] = fmaf(fa, wg0[cc*16+j], p0[j]);
#pragma unroll
      for (int j = 0; j < 8; ++j) t8[j] = fmaf(fb, wg1[cc*8+j], t8[j]);
    }
  }
#pragma unroll
  for (int j = 0; j < 8; ++j) t8[j] = fmaxf(t8[j], 0.f);
  float p1[4];
#pragma unroll
  for (int j = 0; j < 4; ++j) p1[j] = b12[cg*4+j];
#pragma unroll
  for (int cc = 0; cc < 8; ++cc){
#pragma unroll
    for (int j = 0; j < 4; ++j) p1[j] = fmaf(t8[cc], W12_l[cc*16 + cg*4 + j], p1[j]);
  }
  float4* o0 = (float4*)(fout + (size_t)row*32 + cg*4);
  float4* o1 = (float4*)(fout + (size_t)row*32 + 16 + cg*4);
  float4 v0 = *o0, v1 = *o1;
  v0.x+=p0[0]; v0.y+=p0[1]; v0.z+=p0[2]; v0.w+=p0[3];
  v1.x+=p1[0]; v1.y+=p1[1]; v1.z+=p1[2]; v1.w+=p1[3];
  *o0 = v0; *o1 = v1;
}

// ---------- cls: 32->1; grid (N/512) ----------
__global__ __launch_bounds__(512) void k_cls(const float* __restrict__ fO,
    const float* __restrict__ WqC, const float* __restrict__ Wcls,
    const float* __restrict__ bc,
    const int* __restrict__ cnt, const int* __restrict__ rem,
    float* __restrict__ cls, int N){
  __shared__ float Ws[LDS32];
  stage32(Ws, fO, blockIdx.x);
  __syncthreads();
  int o = __builtin_amdgcn_readfirstlane(threadIdx.x >> 6);
  int p = threadIdx.x & 63;
  int row = blockIdx.x*512 + p*8 + o;
  const float* wb = WqC + o*256;   // uniform
  float acc = 0.f;
#pragma unroll 1
  for (int op = 0; op < 8; ++op){
    const float* fvp = &Ws[op*CS32 + p*PS32];
    const float* wop = wb + op*32;
#pragma unroll
    for (int cc = 0; cc < 32; ++cc) acc = fmaf(fvp[cc], wop[cc], acc);
  }
  int nrm = cnt[row];
  for (int s = 0; s < nrm; ++s){
    int e = rem[(size_t)row*20 + s];
    int kk = e & 31, jr = e >> 5;
    const float* fr = fO + (size_t)jr*32;
    const float* wg = Wcls + kk*32;
#pragma unroll
    for (int cc = 0; cc < 32; ++cc) acc = fmaf(fr[cc], wg[cc], acc);
  }
  cls[row] = acc + bc[0];
}

// ---------- max/argmax (first-index tie-break) ----------
__global__ void k_reduce1(const float* __restrict__ s, float* __restrict__ pmax,
                          int* __restrict__ pidx, int n){
  __shared__ float sm[256]; __shared__ int si[256];
  int t = threadIdx.x;
  float v = -INFINITY; int vi = 0x7fffffff;
  for (int j = blockIdx.x*256 + t; j < n; j += gridDim.x*256){
    float w = s[j];
    if (w > v){ v = w; vi = j; }
  }
  sm[t] = v; si[t] = vi; __syncthreads();
  for (int o = 128; o > 0; o >>= 1){
    if (t < o){
      if (sm[t+o] > sm[t] || (sm[t+o] == sm[t] && si[t+o] < si[t])){ sm[t]=sm[t+o]; si[t]=si[t+o]; }
    }
    __syncthreads();
  }
  if (t == 0){ pmax[blockIdx.x] = sm[0]; pidx[blockIdx.x] = si[0]; }
}

__global__ void k_reduce2(const float* __restrict__ pmax, const int* __restrict__ pidx,
                          float* __restrict__ g, int nb){
  __shared__ float sm[256]; __shared__ int si[256];
  int t = threadIdx.x;
  sm[t] = (t < nb) ? pmax[t] : -INFINITY;
  si[t] = (t < nb) ? pidx[t] : 0x7fffffff;
  __syncthreads();
  for (int o = 128; o > 0; o >>= 1){
    if (t < o){
      if (sm[t+o] > sm[t] || (sm[t+o] == sm[t] && si[t+o] < si[t])){ sm[t]=sm[t+o]; si[t]=si[t+o]; }
    }
    __syncthreads();
  }
  if (t == 0){ g[0] = sm[0]; ((int*)g)[1] = si[0]; }
}

// ---------- finalize ----------
__global__ void k_final(const float* __restrict__ out, const float* __restrict__ cls,
                        const int* __restrict__ target, const float* __restrict__ g,
                        float* __restrict__ dout, int n_out){
  int idx = blockIdx.x*blockDim.x + threadIdx.x;
  if (idx >= n_out*32) return;
  int row = idx >> 5, c = idx & 31;
  float s = cls[row];
  bool keep = s > 0.f;
  if (g[0] < 0.f) keep = keep || (row == ((const int*)g)[1]);
  float km = keep ? 1.f : 0.f;
  dout[idx] = out[idx] * km;
  if (c == 0){
    dout[(size_t)n_out*32 + row] = s;
    dout[(size_t)n_out*33 + row] = (target[row] != 0) ? 1.f : 0.f;
    dout[(size_t)n_out*34 + row] = km;
  }
}

extern "C" void kernel_launch(void* const* d_in, const int* in_sizes, int n_in,
                              void* d_out, int out_size, void* d_ws, size_t ws_size,
                              hipStream_t stream){
  const float* x      = (const float*)d_in[0];
  const float* W_up   = (const float*)d_in[1];
  const float* b_up   = (const float*)d_in[2];
  const float* W_conv = (const float*)d_in[3];
  const float* b_conv = (const float*)d_in[4];
  const float* Wb00   = (const float*)d_in[5];
  const float* bb00   = (const float*)d_in[6];
  const float* Wb01   = (const float*)d_in[7];
  const float* bb01   = (const float*)d_in[8];
  const float* Wb10   = (const float*)d_in[9];
  const float* bb10   = (const float*)d_in[10];
  const float* Wb11   = (const float*)d_in[11];
  const float* bb11   = (const float*)d_in[12];
  const float* Wb12   = (const float*)d_in[13];
  const float* bb12   = (const float*)d_in[14];
  const float* W_cls  = (const float*)d_in[15];
  const float* b_cls  = (const float*)d_in[16];
  const int*   nbr_in = (const int*)d_in[17];
  const int*   nbr_out= (const int*)d_in[18];
  const int*   target = (const int*)d_in[19];

  const int N = in_sizes[19];        // 65536
  const int P = in_sizes[17] / 27;
  const int pairsT = 27 * P;
  const int Nn = N / 8;              // 8192

  int*   cnt  = (int*)d_ws;                          // N
  int*   rem  = cnt + N;                             // N*20
  float* Wq1  = (float*)(rem + (size_t)N*20);        // 65536
  float* WqA  = Wq1 + 65536;                         // 49152
  float* WqB0 = WqA + 49152;                         // 24576
  float* WqB1 = WqB0 + 24576;                        // 12288
  float* WqC  = WqB1 + 12288;                        // 2048
  float* f_tmp = WqC + 2048;                         // N*32
  float* f_out = f_tmp + (size_t)N*32;               // N*32
  float* a8    = f_out + (size_t)N*32;               // N*8
  float* b8    = a8 + (size_t)N*8;                   // N*8
  float* cls   = b8 + (size_t)N*8;                   // N
  float* pmax  = cls + N;                            // 256
  int*   pidx  = (int*)(pmax + 256);                 // 256
  float* gm    = pmax + 512;                         // [max, argmax]

  const int B = 256;

  k_rinit<<<cdiv(N,B),B,0,stream>>>(cnt, N);
  k_rbuild<<<cdiv((long long)pairsT,B),B,0,stream>>>(nbr_in, nbr_out, cnt, rem, P, N);
  k_repack<<<600,B,0,stream>>>(W_conv, Wb00, Wb01, Wb11, W_cls, Wq1, WqA, WqB0, WqB1, WqC);

  k_up<<<dim3(Nn/64,8),512,0,stream>>>(x, W_up, b_up, f_tmp, Nn);

  k_conv1<<<dim3(N/512,4),512,0,stream>>>(f_tmp, Wq1, W_conv, b_conv, cnt, rem, f_out, N);

  for (int l = 0; l < 3; ++l){
    k_blk_a<<<dim3(N/512,2),512,0,stream>>>(f_out,
        WqA + (size_t)l*16384, Wb00 + (size_t)l*6912, bb00 + l*8,
        Wb10 + (size_t)l*256, bb10 + l*8, cnt, rem, a8, b8, N);
    k_blk_b<<<dim3(N/512,4),512,0,stream>>>(a8, b8,
        WqB0 + (size_t)l*8192, Wb01 + (size_t)l*3456, bb01 + l*16,
        WqB1 + (size_t)l*4096, Wb11 + (size_t)l*1728, bb11 + l*8,
        Wb12 + (size_t)l*128, bb12 + l*16, cnt, rem, f_out, N);
  }

  k_cls<<<N/512,512,0,stream>>>(f_out, WqC, W_cls, b_cls, cnt, rem, cls, N);

  k_reduce1<<<256,256,0,stream>>>(cls, pmax, pidx, N);
  k_reduce2<<<1,256,0,stream>>>(pmax, pidx, gm, 256);

  k_final<<<cdiv((long long)N*32,B),B,0,stream>>>(f_out, cls, target, gm, (float*)d_out, N);
}